// Round 8
// baseline (293.487 us; speedup 1.0000x reference)
//
#include <hip/hip_runtime.h>
#include <math.h>

// Chamfer distance, B=4, N=M=8192, fp32.
// Output layout (flat float32): dist1[B*N], dist2[B*M], idx1[B*N] (as float),
// idx2[B*M] (as float).
//
// R7: (a) monotone-form screening: minimize t = |p|^2 - 2 q.p (== d - |q|^2)
// at 3 fma/eval (+|p|^2 amortized over 4 queries). Group-of-8 min tree picks
// a winning group; top-2 group-min tracking (bd2) guards against t-rounding
// flips: if bd2-bd < eps=1e-5 (>> 2.4e-6 error bound) the split is rescanned
// with the exact canonical d = fmaf(dx,dx,fmaf(dy,dy,dz*dz)); otherwise the
// winning group is resolved exactly (8 exact d, min tree, first-match scan).
// All values entering the cross-split u64 atomicMin are exact d ->
// first-occurrence argmin preserved end-to-end.
// (b) finalize folded into main: per (dir,b,qtile) column counter (ACQ_REL,
// agent scope); last of the 32 split-blocks re-reads the 1024 pp slots with
// agent-scope atomic loads and writes dist/idx. Removes the final kernel.

#define QPT 4         // queries per thread
#define BLK 256       // threads per block
#define QPB (QPT*BLK) // queries per block = 1024

__global__ __launch_bounds__(256) void chamfer_init(
    unsigned long long* __restrict__ pp, int nslots,
    unsigned* __restrict__ cnt, int ncols)
{
    int i = blockIdx.x * blockDim.x + threadIdx.x;
    if (i < nslots) pp[i] = ~0ULL;
    if (i < ncols) cnt[i] = 0u;
}

__global__ __launch_bounds__(256, 4) void chamfer_main(
    const float* __restrict__ xyz1, const float* __restrict__ xyz2,
    unsigned long long* __restrict__ pp, unsigned* __restrict__ cnt,
    float* __restrict__ out, int N, int M, int B, int S, int C)
{
    const int dir = blockIdx.z;          // 0: xyz1->xyz2, 1: xyz2->xyz1
    const float* q = dir ? xyz2 : xyz1;  // query cloud
    const float* r = dir ? xyz1 : xyz2;  // reference cloud
    const int Nq = dir ? M : N;
    const int Nr = dir ? N : M;
    const int b     = blockIdx.y / S;
    const int split = blockIdx.y % S;
    const int base  = split * C;         // this block's ref-index range [base, base+C)

    extern __shared__ float s[];         // C*3 floats
    __shared__ int lastFlag;

    // cooperative vectorized tile load (C%8==0 -> byte count divisible by 16)
    {
        const float4* gv = (const float4*)(r + ((size_t)b * Nr + base) * 3);
        float4* sv = (float4*)s;
        const int elems4 = C * 3 / 4;
        for (int t = threadIdx.x; t < elems4; t += BLK) sv[t] = gv[t];
    }
    __syncthreads();

    // load 4 query points; precompute -2q for the monotone form
    float qx[QPT], qy[QPT], qz[QPT];
    float n2x[QPT], n2y[QPT], n2z[QPT];
    int qi[QPT];
    bool qv[QPT];
#pragma unroll
    for (int k = 0; k < QPT; ++k) {
        qi[k] = blockIdx.x * QPB + k * BLK + threadIdx.x;
        qv[k] = qi[k] < Nq;
        const float* qp = q + ((size_t)b * Nq + (qv[k] ? qi[k] : 0)) * 3;
        qx[k] = qp[0]; qy[k] = qp[1]; qz[k] = qp[2];
        n2x[k] = -2.0f * qx[k]; n2y[k] = -2.0f * qy[k]; n2z[k] = -2.0f * qz[k];
    }

    // per-query: best group-min t, its group id, and second-best group-min t
    float bd[QPT], bd2[QPT];
    int   gi[QPT];
#pragma unroll
    for (int k = 0; k < QPT; ++k) { bd[k] = INFINITY; bd2[k] = INFINITY; gi[k] = 0; }

    const float4* sv = (const float4*)s;
    const int iters = C / 8;
    for (int j8 = 0; j8 < iters; ++j8) {
        float4 f0 = sv[6 * j8 + 0];
        float4 f1 = sv[6 * j8 + 1];
        float4 f2 = sv[6 * j8 + 2];
        float4 f3 = sv[6 * j8 + 3];
        float4 f4 = sv[6 * j8 + 4];
        float4 f5 = sv[6 * j8 + 5];
        float px[8] = { f0.x, f0.w, f1.z, f2.y, f3.x, f3.w, f4.z, f5.y };
        float py[8] = { f0.y, f1.x, f1.w, f2.z, f3.y, f4.x, f4.w, f5.z };
        float pz[8] = { f0.z, f1.y, f2.x, f2.w, f3.z, f4.y, f5.x, f5.w };
        // |p|^2 once per point, shared across this thread's 4 queries
        float u[8];
#pragma unroll
        for (int p = 0; p < 8; ++p)
            u[p] = fmaf(pz[p], pz[p], fmaf(py[p], py[p], px[p] * px[p]));
#pragma unroll
        for (int k = 0; k < QPT; ++k) {
            float t[8];
#pragma unroll
            for (int p = 0; p < 8; ++p)
                t[p] = fmaf(n2x[k], px[p],
                       fmaf(n2y[k], py[p],
                       fmaf(n2z[k], pz[p], u[p])));
            // nested mins fold to v_min3 chains
            float m = fminf(fminf(fminf(fminf(fminf(fminf(fminf(
                t[0], t[1]), t[2]), t[3]), t[4]), t[5]), t[6]), t[7]);
            float old = bd[k];
            bool c = m < old;                       // strict: earliest group kept
            bd[k]  = c ? m : old;
            gi[k]  = c ? j8 : gi[k];
            bd2[k] = fminf(bd2[k], fmaxf(old, m));  // second-best group-min
        }
    }

    // resolve each query exactly and fold into global slot via u64 atomicMin
    const size_t obase = (size_t)(dir * B + b) * Nq;
    const float eps = 1e-5f;  // >> 2.4e-6 t-rounding bound
#pragma unroll
    for (int k = 0; k < QPT; ++k) {
        if (!qv[k]) continue;
        unsigned long long packed;
        if (bd2[k] - bd[k] < eps) {
            // ambiguous across groups: exact first-occurrence rescan of the
            // whole chunk (uniform addresses -> LDS broadcast, no conflicts)
            float best = INFINITY; int bidx = 0;
            for (int j = 0; j < C; ++j) {
                float dx = qx[k] - s[3 * j + 0];
                float dy = qy[k] - s[3 * j + 1];
                float dz = qz[k] - s[3 * j + 2];
                float d = fmaf(dx, dx, fmaf(dy, dy, dz * dz));
                if (d < best) { best = d; bidx = j; }
            }
            packed = ((unsigned long long)__float_as_uint(best) << 32)
                   | (unsigned)(base + bidx);
        } else {
            // winner group is unambiguous: resolve its 8 points exactly
            const int g = gi[k];
            float4 f0 = sv[6 * g + 0];
            float4 f1 = sv[6 * g + 1];
            float4 f2 = sv[6 * g + 2];
            float4 f3 = sv[6 * g + 3];
            float4 f4 = sv[6 * g + 4];
            float4 f5 = sv[6 * g + 5];
            float px[8] = { f0.x, f0.w, f1.z, f2.y, f3.x, f3.w, f4.z, f5.y };
            float py[8] = { f0.y, f1.x, f1.w, f2.z, f3.y, f4.x, f4.w, f5.z };
            float pz[8] = { f0.z, f1.y, f2.x, f2.w, f3.z, f4.y, f5.x, f5.w };
            float d[8];
#pragma unroll
            for (int p = 0; p < 8; ++p) {
                float dx = qx[k] - px[p];
                float dy = qy[k] - py[p];
                float dz = qz[k] - pz[p];
                d[p] = fmaf(dx, dx, fmaf(dy, dy, dz * dz));
            }
            float m = fminf(fminf(fminf(fminf(fminf(fminf(fminf(
                d[0], d[1]), d[2]), d[3]), d[4]), d[5]), d[6]), d[7]);
            int best = 0;
#pragma unroll
            for (int p = 7; p >= 0; --p)      // descending: smallest match wins
                if (d[p] == m) best = p;      // bitwise match guaranteed
            packed = ((unsigned long long)__float_as_uint(m) << 32)
                   | (unsigned)(base + g * 8 + best);
        }
        atomicMin(&pp[obase + qi[k]], packed);
    }

    // ---- fused finalize: last split-block of this (dir,b,qtile) column ----
    __syncthreads();  // s_waitcnt vmcnt(0) precedes barrier: atomicMins drained
    if (threadIdx.x == 0) {
        const int col = (dir * B + b) * gridDim.x + blockIdx.x;
        unsigned old = __hip_atomic_fetch_add(&cnt[col], 1u,
                          __ATOMIC_ACQ_REL, __HIP_MEMORY_SCOPE_AGENT);
        lastFlag = (old == (unsigned)(S - 1));
    }
    __syncthreads();
    if (lastFlag) {
        float* dist_out = out + (dir ? (size_t)B * N : 0);
        float* idx_out  = out + (size_t)B * N + (size_t)B * M
                              + (dir ? (size_t)B * N : 0);
#pragma unroll
        for (int k = 0; k < QPT; ++k) {
            if (!qv[k]) continue;
            unsigned long long v = __hip_atomic_load(&pp[obase + qi[k]],
                    __ATOMIC_RELAXED, __HIP_MEMORY_SCOPE_AGENT);
            dist_out[(size_t)b * Nq + qi[k]] = __uint_as_float((unsigned)(v >> 32));
            idx_out[(size_t)b * Nq + qi[k]]  = (float)(unsigned)(v & 0xffffffffu);
        }
    }
}

extern "C" void kernel_launch(void* const* d_in, const int* in_sizes, int n_in,
                              void* d_out, int out_size, void* d_ws, size_t ws_size,
                              hipStream_t stream) {
    const float* xyz1 = (const float*)d_in[0];
    const float* xyz2 = (const float*)d_in[1];
    float* out = (float*)d_out;
    const int B = 4;
    const int N = in_sizes[0] / (B * 3);
    const int M = in_sizes[1] / (B * 3);
    const int NQ = (N > M ? N : M);
    const int NR = (N > M ? N : M);

    int S = 32;
    while (NR % (S * 8)) S >>= 1;  // need C = NR/S divisible by 8
    const int C = NR / S;

    unsigned long long* pp = (unsigned long long*)d_ws;  // [2][B][NQ] packed
    const int nslots = 2 * B * NQ;
    const int nqt = (NQ + QPB - 1) / QPB;                // query tiles
    unsigned* cnt = (unsigned*)((char*)d_ws + (size_t)nslots * 8);
    const int ncols = 2 * B * nqt;

    const int initN = (nslots > ncols ? nslots : ncols);
    chamfer_init<<<dim3((initN + 255) / 256, 1, 1), dim3(256, 1, 1), 0, stream>>>(
        pp, nslots, cnt, ncols);

    dim3 grid(nqt, B * S, 2);
    size_t lds = (size_t)C * 3 * sizeof(float);
    chamfer_main<<<grid, dim3(BLK, 1, 1), lds, stream>>>(
        xyz1, xyz2, pp, cnt, out, N, M, B, S, C);
}

// Round 9
// 263.659 us; speedup vs baseline: 1.1131x; 1.1131x over previous
//
#include <hip/hip_runtime.h>
#include <math.h>

// Chamfer distance, B=4, N=M=8192, fp32.
// Output layout (flat float32): dist1[B*N], dist2[B*M], idx1[B*N] (as float),
// idx2[B*M] (as float).
//
// R8: revert R7's monotone-form inner loop — its large live set (u/t/bd2 +
// 24 tile floats) made the occupancy-greedy allocator cap VGPRs at 40 and
// re-materialize tile data from LDS inside the k-loop (~100 scalar ds_reads
// per iter -> lgkm-stall-bound, VALUBusy 30%, 3x regression). Back to the
// proven R6 inner loop: exact d = fmaf(dx,dx,fmaf(dy,dy,dz*dz)) (absmax 0),
// group-of-8 min tree, winner resolved by deterministic recompute.
// KEEP R7's fused finalize: per (dir,b,qtile) column counter (agent scope);
// the last of the 32 split-blocks re-reads the column's pp slots and writes
// dist/idx — deletes the final kernel + one launch gap.

#define QPT 4         // queries per thread
#define BLK 256       // threads per block
#define QPB (QPT*BLK) // queries per block = 1024

__global__ __launch_bounds__(256) void chamfer_init(
    unsigned long long* __restrict__ pp, int nslots,
    unsigned* __restrict__ cnt, int ncols)
{
    int i = blockIdx.x * blockDim.x + threadIdx.x;
    if (i < nslots) pp[i] = ~0ULL;
    if (i < ncols) cnt[i] = 0u;
}

__global__ __launch_bounds__(256, 4) void chamfer_main(
    const float* __restrict__ xyz1, const float* __restrict__ xyz2,
    unsigned long long* __restrict__ pp, unsigned* __restrict__ cnt,
    float* __restrict__ out, int N, int M, int B, int S, int C)
{
    const int dir = blockIdx.z;          // 0: xyz1->xyz2, 1: xyz2->xyz1
    const float* q = dir ? xyz2 : xyz1;  // query cloud
    const float* r = dir ? xyz1 : xyz2;  // reference cloud
    const int Nq = dir ? M : N;
    const int Nr = dir ? N : M;
    const int b     = blockIdx.y / S;
    const int split = blockIdx.y % S;
    const int base  = split * C;         // this block's ref-index range [base, base+C)

    extern __shared__ float s[];         // C*3 floats
    __shared__ int lastFlag;

    // cooperative vectorized tile load (C%8==0 -> byte count divisible by 16)
    {
        const float4* gv = (const float4*)(r + ((size_t)b * Nr + base) * 3);
        float4* sv = (float4*)s;
        const int elems4 = C * 3 / 4;
        for (int t = threadIdx.x; t < elems4; t += BLK) sv[t] = gv[t];
    }
    __syncthreads();

    // load 4 query points (stride-BLK within the block's query window)
    float qx[QPT], qy[QPT], qz[QPT];
    int qi[QPT];
    bool qv[QPT];
#pragma unroll
    for (int k = 0; k < QPT; ++k) {
        qi[k] = blockIdx.x * QPB + k * BLK + threadIdx.x;
        qv[k] = qi[k] < Nq;
        const float* qp = q + ((size_t)b * Nq + (qv[k] ? qi[k] : 0)) * 3;
        qx[k] = qp[0]; qy[k] = qp[1]; qz[k] = qp[2];
    }

    // per-query running min + winning 8-group id
    float bd[QPT];
    int   gi[QPT];
#pragma unroll
    for (int k = 0; k < QPT; ++k) { bd[k] = INFINITY; gi[k] = 0; }

    const float4* sv = (const float4*)s;
    const int iters = C / 8;
    for (int j8 = 0; j8 < iters; ++j8) {
        // 24 floats = 8 ref points; all lanes same address -> LDS broadcast
        float4 f0 = sv[6 * j8 + 0];
        float4 f1 = sv[6 * j8 + 1];
        float4 f2 = sv[6 * j8 + 2];
        float4 f3 = sv[6 * j8 + 3];
        float4 f4 = sv[6 * j8 + 4];
        float4 f5 = sv[6 * j8 + 5];
        float px[8] = { f0.x, f0.w, f1.z, f2.y, f3.x, f3.w, f4.z, f5.y };
        float py[8] = { f0.y, f1.x, f1.w, f2.z, f3.y, f4.x, f4.w, f5.z };
        float pz[8] = { f0.z, f1.y, f2.x, f2.w, f3.z, f4.y, f5.x, f5.w };
#pragma unroll
        for (int k = 0; k < QPT; ++k) {
            float d[8];
#pragma unroll
            for (int p = 0; p < 8; ++p) {
                float dx = qx[k] - px[p];
                float dy = qy[k] - py[p];
                float dz = qz[k] - pz[p];
                d[p] = fmaf(dx, dx, fmaf(dy, dy, dz * dz));
            }
            // min-of-8 tree (compiler folds fminf pairs/triples into v_min3)
            float m01 = fminf(d[0], d[1]);
            float m23 = fminf(d[2], d[3]);
            float m45 = fminf(d[4], d[5]);
            float m67 = fminf(d[6], d[7]);
            float m = fminf(fminf(m01, m23), fminf(m45, m67));
            // strict < keeps the EARLIEST group attaining the min value
            if (m < bd[k]) { bd[k] = m; gi[k] = j8; }
        }
    }

    // resolve intra-group index of the winner by deterministic recompute
    // (same fmaf expression on the same LDS data -> bitwise identical d),
    // then fold into the global per-query slot via u64 atomicMin.
    const size_t obase = (size_t)(dir * B + b) * Nq;
#pragma unroll
    for (int k = 0; k < QPT; ++k) {
        if (!qv[k]) continue;
        const int g = gi[k];
        float4 f0 = sv[6 * g + 0];
        float4 f1 = sv[6 * g + 1];
        float4 f2 = sv[6 * g + 2];
        float4 f3 = sv[6 * g + 3];
        float4 f4 = sv[6 * g + 4];
        float4 f5 = sv[6 * g + 5];
        float px[8] = { f0.x, f0.w, f1.z, f2.y, f3.x, f3.w, f4.z, f5.y };
        float py[8] = { f0.y, f1.x, f1.w, f2.z, f3.y, f4.x, f4.w, f5.z };
        float pz[8] = { f0.z, f1.y, f2.x, f2.w, f3.z, f4.y, f5.x, f5.w };
        int best = 0;
#pragma unroll
        for (int p = 7; p >= 0; --p) {   // descending: ends at SMALLEST match
            float dx = qx[k] - px[p];
            float dy = qy[k] - py[p];
            float dz = qz[k] - pz[p];
            float d = fmaf(dx, dx, fmaf(dy, dy, dz * dz));
            if (d == bd[k]) best = p;    // match guaranteed (same bits)
        }
        const int idx = base + g * 8 + best;
        // d >= 0 -> float bits order-monotonic as unsigned.
        unsigned long long packed =
            ((unsigned long long)__float_as_uint(bd[k]) << 32) | (unsigned)idx;
        atomicMin(&pp[obase + qi[k]], packed);
    }

    // ---- fused finalize: last split-block of this (dir,b,qtile) column ----
    __syncthreads();  // barrier drain: this block's atomicMins are in flight->done
    if (threadIdx.x == 0) {
        const int col = (dir * B + b) * gridDim.x + blockIdx.x;
        unsigned old = __hip_atomic_fetch_add(&cnt[col], 1u,
                          __ATOMIC_ACQ_REL, __HIP_MEMORY_SCOPE_AGENT);
        lastFlag = (old == (unsigned)(S - 1));
    }
    __syncthreads();
    if (lastFlag) {
        float* dist_out = out + (dir ? (size_t)B * N : 0);
        float* idx_out  = out + (size_t)B * N + (size_t)B * M
                              + (dir ? (size_t)B * N : 0);
#pragma unroll
        for (int k = 0; k < QPT; ++k) {
            if (!qv[k]) continue;
            unsigned long long v = __hip_atomic_load(&pp[obase + qi[k]],
                    __ATOMIC_RELAXED, __HIP_MEMORY_SCOPE_AGENT);
            dist_out[(size_t)b * Nq + qi[k]] = __uint_as_float((unsigned)(v >> 32));
            idx_out[(size_t)b * Nq + qi[k]]  = (float)(unsigned)(v & 0xffffffffu);
        }
    }
}

extern "C" void kernel_launch(void* const* d_in, const int* in_sizes, int n_in,
                              void* d_out, int out_size, void* d_ws, size_t ws_size,
                              hipStream_t stream) {
    const float* xyz1 = (const float*)d_in[0];
    const float* xyz2 = (const float*)d_in[1];
    float* out = (float*)d_out;
    const int B = 4;
    const int N = in_sizes[0] / (B * 3);
    const int M = in_sizes[1] / (B * 3);
    const int NQ = (N > M ? N : M);
    const int NR = (N > M ? N : M);

    int S = 32;
    while (NR % (S * 8)) S >>= 1;  // need C = NR/S divisible by 8
    const int C = NR / S;

    unsigned long long* pp = (unsigned long long*)d_ws;  // [2][B][NQ] packed
    const int nslots = 2 * B * NQ;
    const int nqt = (NQ + QPB - 1) / QPB;                // query tiles
    unsigned* cnt = (unsigned*)((char*)d_ws + (size_t)nslots * 8);
    const int ncols = 2 * B * nqt;

    const int initN = (nslots > ncols ? nslots : ncols);
    chamfer_init<<<dim3((initN + 255) / 256, 1, 1), dim3(256, 1, 1), 0, stream>>>(
        pp, nslots, cnt, ncols);

    dim3 grid(nqt, B * S, 2);
    size_t lds = (size_t)C * 3 * sizeof(float);
    chamfer_main<<<grid, dim3(BLK, 1, 1), lds, stream>>>(
        xyz1, xyz2, pp, cnt, out, N, M, B, S, C);
}

// Round 10
// 123.459 us; speedup vs baseline: 2.3772x; 2.1356x over previous
//
#include <hip/hip_runtime.h>
#include <math.h>

// Chamfer distance, B=4, N=M=8192, fp32.
// Output layout (flat float32): dist1[B*N], dist2[B*M], idx1[B*N] (as float),
// idx2[B*M] (as float).
//
// R9: EXACT R6 main + final kernels (proven 78 us main; R7/R8 showed that
// touching main's epilogue — fused finalize / monotone form — triggers
// compiler codegen pathologies: LDS rematerialization or scheduling collapse,
// 3x regressions). Tail shaved by replacing the init kernel with a
// hipMemsetAsync(pp, 0xFF) node: byte pattern 0xFF == ~0ULL per u64 slot,
// which is the exact init value. One fewer kernel dispatch + gap.
//
// Semantics: d = fmaf(dx,dx,fmaf(dy,dy,dz*dz)) (rounding delta ~ulp(d) vs
// reference, flip-safe: ~2300x below typical top-2 gaps -> absmax 0 measured
// in R5-R8). Group-of-8 min tree + strict < keeps earliest group; winner
// resolved by deterministic recompute (bitwise-identical d), descending scan
// -> smallest index; u64 atomicMin of (dist_bits<<32|idx) tie-breaks to
// lower global index == np.argmin first-occurrence.

#define QPT 4         // queries per thread
#define BLK 256       // threads per block
#define QPB (QPT*BLK) // queries per block = 1024

__global__ __launch_bounds__(256, 4) void chamfer_main(
    const float* __restrict__ xyz1, const float* __restrict__ xyz2,
    unsigned long long* __restrict__ pp,
    int N, int M, int B, int S, int C)
{
    const int dir = blockIdx.z;          // 0: xyz1->xyz2, 1: xyz2->xyz1
    const float* q = dir ? xyz2 : xyz1;  // query cloud
    const float* r = dir ? xyz1 : xyz2;  // reference cloud
    const int Nq = dir ? M : N;
    const int Nr = dir ? N : M;
    const int b     = blockIdx.y / S;
    const int split = blockIdx.y % S;
    const int base  = split * C;         // this block's ref-index range [base, base+C)

    extern __shared__ float s[];         // C*3 floats

    // cooperative vectorized tile load (C%8==0 -> byte count divisible by 16)
    {
        const float4* gv = (const float4*)(r + ((size_t)b * Nr + base) * 3);
        float4* sv = (float4*)s;
        const int elems4 = C * 3 / 4;
        for (int t = threadIdx.x; t < elems4; t += BLK) sv[t] = gv[t];
    }
    __syncthreads();

    // load 4 query points (stride-BLK within the block's query window)
    float qx[QPT], qy[QPT], qz[QPT];
    int qi[QPT];
    bool qv[QPT];
#pragma unroll
    for (int k = 0; k < QPT; ++k) {
        qi[k] = blockIdx.x * QPB + k * BLK + threadIdx.x;
        qv[k] = qi[k] < Nq;
        const float* qp = q + ((size_t)b * Nq + (qv[k] ? qi[k] : 0)) * 3;
        qx[k] = qp[0]; qy[k] = qp[1]; qz[k] = qp[2];
    }

    // per-query running min + winning 8-group id
    float bd[QPT];
    int   gi[QPT];
#pragma unroll
    for (int k = 0; k < QPT; ++k) { bd[k] = INFINITY; gi[k] = 0; }

    const float4* sv = (const float4*)s;
    const int iters = C / 8;
    for (int j8 = 0; j8 < iters; ++j8) {
        // 24 floats = 8 ref points; all lanes same address -> LDS broadcast
        float4 f0 = sv[6 * j8 + 0];
        float4 f1 = sv[6 * j8 + 1];
        float4 f2 = sv[6 * j8 + 2];
        float4 f3 = sv[6 * j8 + 3];
        float4 f4 = sv[6 * j8 + 4];
        float4 f5 = sv[6 * j8 + 5];
        float px[8] = { f0.x, f0.w, f1.z, f2.y, f3.x, f3.w, f4.z, f5.y };
        float py[8] = { f0.y, f1.x, f1.w, f2.z, f3.y, f4.x, f4.w, f5.z };
        float pz[8] = { f0.z, f1.y, f2.x, f2.w, f3.z, f4.y, f5.x, f5.w };
#pragma unroll
        for (int k = 0; k < QPT; ++k) {
            float d[8];
#pragma unroll
            for (int p = 0; p < 8; ++p) {
                float dx = qx[k] - px[p];
                float dy = qy[k] - py[p];
                float dz = qz[k] - pz[p];
                d[p] = fmaf(dx, dx, fmaf(dy, dy, dz * dz));
            }
            // min-of-8 tree (compiler folds fminf pairs/triples into v_min3)
            float m01 = fminf(d[0], d[1]);
            float m23 = fminf(d[2], d[3]);
            float m45 = fminf(d[4], d[5]);
            float m67 = fminf(d[6], d[7]);
            float m = fminf(fminf(m01, m23), fminf(m45, m67));
            // strict < keeps the EARLIEST group attaining the min value
            if (m < bd[k]) { bd[k] = m; gi[k] = j8; }
        }
    }

    // resolve intra-group index of the winner by deterministic recompute
    // (same fmaf expression on the same LDS data -> bitwise identical d),
    // then fold into the global per-query slot via u64 atomicMin.
    const size_t obase = (size_t)(dir * B + b) * Nq;
#pragma unroll
    for (int k = 0; k < QPT; ++k) {
        if (!qv[k]) continue;
        const int g = gi[k];
        float4 f0 = sv[6 * g + 0];
        float4 f1 = sv[6 * g + 1];
        float4 f2 = sv[6 * g + 2];
        float4 f3 = sv[6 * g + 3];
        float4 f4 = sv[6 * g + 4];
        float4 f5 = sv[6 * g + 5];
        float px[8] = { f0.x, f0.w, f1.z, f2.y, f3.x, f3.w, f4.z, f5.y };
        float py[8] = { f0.y, f1.x, f1.w, f2.z, f3.y, f4.x, f4.w, f5.z };
        float pz[8] = { f0.z, f1.y, f2.x, f2.w, f3.z, f4.y, f5.x, f5.w };
        int best = 0;
#pragma unroll
        for (int p = 7; p >= 0; --p) {   // descending: ends at SMALLEST match
            float dx = qx[k] - px[p];
            float dy = qy[k] - py[p];
            float dz = qz[k] - pz[p];
            float d = fmaf(dx, dx, fmaf(dy, dy, dz * dz));
            if (d == bd[k]) best = p;    // match guaranteed (same bits)
        }
        const int idx = base + g * 8 + best;
        // d >= 0 -> float bits order-monotonic as unsigned.
        unsigned long long packed =
            ((unsigned long long)__float_as_uint(bd[k]) << 32) | (unsigned)idx;
        atomicMin(&pp[obase + qi[k]], packed);
    }
}

__global__ __launch_bounds__(256) void chamfer_final(
    const unsigned long long* __restrict__ pp,
    float* __restrict__ out, int N, int M, int B)
{
    const int gid = blockIdx.x * blockDim.x + threadIdx.x;
    const int perDir0 = B * N;
    int dir, rem;
    if (gid < perDir0) { dir = 0; rem = gid; }
    else if (gid < perDir0 + B * M) { dir = 1; rem = gid - perDir0; }
    else return;
    const int Nq = dir ? M : N;

    // pp is [2][B][Nq] flat; rem = b*Nq + i
    unsigned long long v = pp[(size_t)(dir * B) * Nq + rem];

    float* dist_out = out + (dir ? (size_t)B * N : 0);
    float* idx_out  = out + (size_t)B * N + (size_t)B * M + (dir ? (size_t)B * N : 0);
    dist_out[rem] = __uint_as_float((unsigned)(v >> 32));
    idx_out[rem]  = (float)(unsigned)(v & 0xffffffffu);
}

extern "C" void kernel_launch(void* const* d_in, const int* in_sizes, int n_in,
                              void* d_out, int out_size, void* d_ws, size_t ws_size,
                              hipStream_t stream) {
    const float* xyz1 = (const float*)d_in[0];
    const float* xyz2 = (const float*)d_in[1];
    float* out = (float*)d_out;
    const int B = 4;
    const int N = in_sizes[0] / (B * 3);
    const int M = in_sizes[1] / (B * 3);
    const int NQ = (N > M ? N : M);
    const int NR = (N > M ? N : M);

    int S = 32;
    while (NR % (S * 8)) S >>= 1;  // need C = NR/S divisible by 8
    const int C = NR / S;

    unsigned long long* pp = (unsigned long long*)d_ws;  // [2][B][NQ] packed slots
    const int nslots = 2 * B * NQ;

    // init pp to ~0ULL via byte-pattern memset (0xFF) — graph-capturable
    // memset node, replaces the init kernel (one fewer dispatch + gap).
    hipMemsetAsync(pp, 0xFF, (size_t)nslots * 8, stream);

    dim3 grid((NQ + QPB - 1) / QPB, B * S, 2);
    size_t lds = (size_t)C * 3 * sizeof(float);
    chamfer_main<<<grid, dim3(BLK, 1, 1), lds, stream>>>(
        xyz1, xyz2, pp, N, M, B, S, C);

    chamfer_final<<<dim3((nslots + 255) / 256, 1, 1), dim3(256, 1, 1), 0, stream>>>(
        pp, out, N, M, B);
}